// Round 4
// baseline (253.981 us; speedup 1.0000x reference)
//
#include <hip/hip_runtime.h>
#include <hip/hip_bf16.h>

#define NB 8
#define NT 2048
#define NE 1024
#define NH 64

typedef __bf16 bf16_t;
typedef __bf16 bf16x8 __attribute__((ext_vector_type(8)));
typedef float f32x4 __attribute__((ext_vector_type(4)));

#define MFMA16(a, b, c) __builtin_amdgcn_mfma_f32_16x16x32_bf16(a, b, c, 0, 0, 0)

static __device__ __forceinline__ f32x4 fzero4() {
    f32x4 z = {0.f, 0.f, 0.f, 0.f};
    return z;
}

// ---------------------------------------------------------------------------
// Kernel 0: convert W (f32) -> bf16 workspace. Wb layout: [0]=Wq, [1]=Wk, [2]=Wv
// ---------------------------------------------------------------------------
__global__ __launch_bounds__(256) void convw_kernel(
    const float* __restrict__ Wq, const float* __restrict__ Wk,
    const float* __restrict__ Wv, bf16_t* __restrict__ Wb)
{
    int src = blockIdx.y;
    const float* W = (src == 0) ? Wq : ((src == 1) ? Wk : Wv);
    int idx = (blockIdx.x * 256 + threadIdx.x) * 8;  // 32 blocks * 256 thr * 8 = 65536
    f32x4 a = *(const f32x4*)(W + idx);
    f32x4 b = *(const f32x4*)(W + idx + 4);
    bf16x8 o;
#pragma unroll
    for (int j = 0; j < 4; ++j) { o[j] = (bf16_t)a[j]; o[4 + j] = (bf16_t)b[j]; }
    *(bf16x8*)(Wb + (size_t)src * (NH * NE) + idx) = o;
}

// ---------------------------------------------------------------------------
// Kernel 1: projections, K-split-4. grid (16384/16, 3), 256 thr.
// Block = one 16-row tile; wave w covers K in [w*256, w*256+256) (8 MFMA
// steps), partials merged through LDS. 12 blocks/CU launched -> 8 resident
// = 8 waves/SIMD for latency hiding (R3 was grid-limited at 3 waves/SIMD).
//   y=0: qh[t][h] = q . Wq   (A = x rows, B = W)
//   y=1: kh[t][h] = k . Wk
//   y=2: vhT[b][h][t] = v . Wv (A = W, B = x -> accumulator is [h][t])
// MFMA 16x16x32 conventions (m89/m91-verified):
//   A-frag: lane holds A[row=lane&15][k=(lane>>4)*8 + j]
//   B-frag: lane holds B[k=(lane>>4)*8 + j][col=lane&15]
//   D:      col = lane&15, row = (lane>>4)*4 + reg
// ---------------------------------------------------------------------------
__global__ __launch_bounds__(256, 8) void proj_kernel(
    const float* __restrict__ q_in, const float* __restrict__ k_in,
    const float* __restrict__ v_in, const bf16_t* __restrict__ Wb,
    bf16_t* __restrict__ qh, bf16_t* __restrict__ kh, bf16_t* __restrict__ vhT)
{
    const int which = blockIdx.y;
    const int w    = threadIdx.x >> 6;   // K-split index 0..3
    const int lane = threadIdx.x & 63;
    const int l15  = lane & 15;
    const int lhi  = lane >> 4;
    const int t0   = blockIdx.x * 16;

    const float*  x = (which == 0) ? q_in : ((which == 1) ? k_in : v_in);
    const bf16_t* W = Wb + (size_t)which * (NH * NE);

    const int kbeg = w * 256;
    const float*  xrow = x + (size_t)(t0 + l15) * NE + kbeg + lhi * 8;
    const bf16_t* wrow = W + (size_t)l15 * NE + kbeg + lhi * 8;

    f32x4 acc[4] = {fzero4(), fzero4(), fzero4(), fzero4()};

    if (which < 2) {
#pragma unroll
        for (int g = 0; g < 8; ++g) {
            const int k0 = g * 32;
            f32x4 xa = *(const f32x4*)(xrow + k0);
            f32x4 xb = *(const f32x4*)(xrow + k0 + 4);
            bf16x8 xf;
#pragma unroll
            for (int j = 0; j < 4; ++j) { xf[j] = (bf16_t)xa[j]; xf[4 + j] = (bf16_t)xb[j]; }
#pragma unroll
            for (int cg = 0; cg < 4; ++cg) {
                bf16x8 bfw = *(const bf16x8*)(wrow + (size_t)cg * 16 * NE + k0);
                acc[cg] = MFMA16(xf, bfw, acc[cg]);
            }
        }
    } else {
#pragma unroll
        for (int g = 0; g < 8; ++g) {
            const int k0 = g * 32;
            f32x4 xa = *(const f32x4*)(xrow + k0);
            f32x4 xb = *(const f32x4*)(xrow + k0 + 4);
            bf16x8 xf;
#pragma unroll
            for (int j = 0; j < 4; ++j) { xf[j] = (bf16_t)xa[j]; xf[4 + j] = (bf16_t)xb[j]; }
#pragma unroll
            for (int hg = 0; hg < 4; ++hg) {
                bf16x8 afw = *(const bf16x8*)(wrow + (size_t)hg * 16 * NE + k0);
                acc[hg] = MFMA16(afw, xf, acc[hg]);
            }
        }
    }

    // ---- merge the 4 K-splits through LDS ------------------------------
    __shared__ float sm[4][64][17];   // [ksplit][dim0][dim1], odd stride

    if (which < 2) {
        // partial is [16 rows][64 cols]; store as sm[w][col][row]
#pragma unroll
        for (int cg = 0; cg < 4; ++cg)
#pragma unroll
            for (int r = 0; r < 4; ++r)
                sm[w][cg * 16 + l15][lhi * 4 + r] = acc[cg][r];
        __syncthreads();
        bf16_t* outp = (which == 0) ? qh : kh;
        const int col = w * 16 + l15;
#pragma unroll
        for (int r = 0; r < 4; ++r) {
            int row = lhi * 4 + r;
            float v = sm[0][col][row] + sm[1][col][row] + sm[2][col][row] + sm[3][col][row];
            outp[(size_t)(t0 + row) * NH + col] = (bf16_t)v;
        }
    } else {
        // partial is [64 h][16 t]; store as sm[w][h][t]
#pragma unroll
        for (int hg = 0; hg < 4; ++hg)
#pragma unroll
            for (int r = 0; r < 4; ++r)
                sm[w][hg * 16 + lhi * 4 + r][l15] = acc[hg][r];
        __syncthreads();
        const int b  = t0 >> 11;
        const int tt = (t0 & 2047) + l15;
#pragma unroll
        for (int r = 0; r < 4; ++r) {
            int h = w * 16 + lhi * 4 + r;
            float v = sm[0][h][l15] + sm[1][h][l15] + sm[2][h][l15] + sm[3][h][l15];
            vhT[(((size_t)(b * NH + h)) << 11) + tt] = (bf16_t)v;
        }
    }
}

// ---------------------------------------------------------------------------
// Kernel 2: split-K flash attention, causal + key-mask.
// grid = (B*T/16) linear blocks, 256 thr. Block owns ONE 16-row q-tile; its
// 4 waves split the causal key range 4 ways (64-key tiles each), then merge
// partial (m, l, O) through LDS.
// ---------------------------------------------------------------------------
__global__ __launch_bounds__(256) void attn_kernel(
    const bf16_t* __restrict__ qh, const bf16_t* __restrict__ kh,
    const bf16_t* __restrict__ vhT, const int* __restrict__ mask,
    float* __restrict__ out)
{
    const int lin  = blockIdx.x;
    const int qt16 = lin >> 3;     // 0..127: q-tile (16 rows)
    const int b    = lin & 7;
    const int w    = threadIdx.x >> 6;   // key-split index 0..3
    const int lane = threadIdx.x & 63;
    const int l15  = lane & 15;
    const int lhi  = lane >> 4;

    __shared__ __align__(16) char plds[4][2][2048];   // [wave][dbuf][16x64 bf16]
    __shared__ float sm_o[4][16][65];                  // [wave][row][col] (+1 pad)
    __shared__ float sm_ml[4][2][16];                  // [wave][m/l][row]

    const int q0  = qt16 * 16;
    const int nkt = (q0 + 15) / 64 + 1;     // causal 64-key tiles
    const int len = (nkt + 3) >> 2;         // ceil(nkt/4)
    const int kt_beg = w * len;
    const int kt_end = min(kt_beg + len, nkt);

    // Q fragments (H=64 -> two k-chunks of 32)
    const bf16_t* qbase = qh + (size_t)(b * NT + q0 + l15) * NH + lhi * 8;
    bf16x8 qf0 = *(const bf16x8*)(qbase);
    bf16x8 qf1 = *(const bf16x8*)(qbase + 32);

    f32x4 acc_o[4] = {fzero4(), fzero4(), fzero4(), fzero4()};
    float m[4]    = {-1e30f, -1e30f, -1e30f, -1e30f};
    float lsum[4] = {0.f, 0.f, 0.f, 0.f};

    const int qq0 = q0 + lhi * 4;  // this lane's first q-row

    for (int kt = kt_beg; kt < kt_end; ++kt) {
        // ---- S = (qh . kh^T) * 0.125, tile 16q x 64k --------------------
        const bf16_t* kbase = kh + (size_t)(b * NT + kt * 64 + l15) * NH + lhi * 8;
        f32x4 s[4] = {fzero4(), fzero4(), fzero4(), fzero4()};
#pragma unroll
        for (int cg = 0; cg < 4; ++cg) {
            bf16x8 kf0 = *(const bf16x8*)(kbase + (size_t)cg * 16 * NH);
            bf16x8 kf1 = *(const bf16x8*)(kbase + (size_t)cg * 16 * NH + 32);
            s[cg] = MFMA16(qf0, kf0, s[cg]);
            s[cg] = MFMA16(qf1, kf1, s[cg]);
        }

        // ---- mask + scale ----------------------------------------------
        int mk[4];
#pragma unroll
        for (int cg = 0; cg < 4; ++cg) mk[cg] = mask[b * NT + kt * 64 + cg * 16 + l15];
#pragma unroll
        for (int cg = 0; cg < 4; ++cg) {
            int kk = kt * 64 + cg * 16 + l15;
#pragma unroll
            for (int r = 0; r < 4; ++r) {
                float sv = s[cg][r] * 0.125f;
                bool ok = (kk <= qq0 + r) && (mk[cg] != 0);
                s[cg][r] = ok ? sv : -1e30f;
            }
        }

        // ---- online softmax (row spread over 16 lanes x 4 cgs) ----------
        float mx[4];
#pragma unroll
        for (int r = 0; r < 4; ++r) {
            mx[r] = fmaxf(fmaxf(s[0][r], s[1][r]), fmaxf(s[2][r], s[3][r]));
#pragma unroll
            for (int d = 1; d < 16; d <<= 1) mx[r] = fmaxf(mx[r], __shfl_xor(mx[r], d));
        }
        float resc[4];
#pragma unroll
        for (int r = 0; r < 4; ++r) {
            float mn = fmaxf(m[r], mx[r]);
            resc[r] = __expf(m[r] - mn);
            m[r] = mn;
        }
        float rs[4] = {0.f, 0.f, 0.f, 0.f};
#pragma unroll
        for (int cg = 0; cg < 4; ++cg)
#pragma unroll
            for (int r = 0; r < 4; ++r) {
                float sv = s[cg][r];
                float p = (sv > -5e29f) ? __expf(sv - m[r]) : 0.f;  // masked -> exactly 0
                s[cg][r] = p;
                rs[r] += p;
            }
#pragma unroll
        for (int r = 0; r < 4; ++r) {
#pragma unroll
            for (int d = 1; d < 16; d <<= 1) rs[r] += __shfl_xor(rs[r], d);
            lsum[r] = lsum[r] * resc[r] + rs[r];
        }
#pragma unroll
        for (int cg = 0; cg < 4; ++cg)
#pragma unroll
            for (int r = 0; r < 4; ++r) acc_o[cg][r] *= resc[r];

        // ---- P -> LDS (bf16, XOR swizzle: byte ^= (row&7)<<4) -----------
        char* pb = &plds[w][kt & 1][0];
#pragma unroll
        for (int cg = 0; cg < 4; ++cg)
#pragma unroll
            for (int r = 0; r < 4; ++r) {
                int row = lhi * 4 + r;
                int col = cg * 16 + l15;
                int byte = (row * 128 + col * 2) ^ ((row & 7) << 4);
                *(bf16_t*)(pb + byte) = (bf16_t)s[cg][r];
            }

        // ---- O += P . V  (A-frags from LDS, B-frags from vhT, contiguous)
        const bf16_t* vbase = vhT + ((size_t)(b * NH + l15) << 11) + kt * 64 + lhi * 8;
#pragma unroll
        for (int kc = 0; kc < 2; ++kc) {
            int row = l15;
            int byte = (row * 128 + kc * 64 + lhi * 16) ^ ((row & 7) << 4);
            bf16x8 pf = *(bf16x8*)(pb + byte);
#pragma unroll
            for (int cg = 0; cg < 4; ++cg) {
                bf16x8 vf = *(const bf16x8*)(vbase + ((size_t)cg * 16 << 11) + kc * 32);
                acc_o[cg] = MFMA16(pf, vf, acc_o[cg]);
            }
        }
    }

    // ---- write this wave's partials to LDS ------------------------------
#pragma unroll
    for (int cg = 0; cg < 4; ++cg)
#pragma unroll
        for (int r = 0; r < 4; ++r)
            sm_o[w][lhi * 4 + r][cg * 16 + l15] = acc_o[cg][r];
    if (l15 == 0) {
#pragma unroll
        for (int r = 0; r < 4; ++r) {
            sm_ml[w][0][lhi * 4 + r] = m[r];
            sm_ml[w][1][lhi * 4 + r] = lsum[r];
        }
    }
    __syncthreads();

    // ---- merge 4 splits; this thread covers col = w*16+l15, rows lhi*4+r
#pragma unroll
    for (int r = 0; r < 4; ++r) {
        int row = lhi * 4 + r;
        float mg = -1e30f;
#pragma unroll
        for (int s = 0; s < 4; ++s) mg = fmaxf(mg, sm_ml[s][0][row]);
        float lg = 0.f, og = 0.f;
#pragma unroll
        for (int s = 0; s < 4; ++s) {
            float e = __expf(sm_ml[s][0][row] - mg);
            lg += e * sm_ml[s][1][row];
            og += e * sm_o[s][row][w * 16 + l15];
        }
        out[(size_t)(b * NT + q0 + row) * NH + w * 16 + l15] = og / lg;
    }
}

// ---------------------------------------------------------------------------
extern "C" void kernel_launch(void* const* d_in, const int* in_sizes, int n_in,
                              void* d_out, int out_size, void* d_ws, size_t ws_size,
                              hipStream_t stream)
{
    const float* k_in = (const float*)d_in[0];
    const float* q_in = (const float*)d_in[1];
    const float* v_in = (const float*)d_in[2];
    const int*   mask = (const int*)d_in[3];
    const float* Wk   = (const float*)d_in[4];
    const float* Wq   = (const float*)d_in[5];
    const float* Wv   = (const float*)d_in[6];
    float* out = (float*)d_out;

    char* ws = (char*)d_ws;
    bf16_t* Wb  = (bf16_t*)ws;                       // 3*64*1024 bf16 = 384 KB
    bf16_t* qh  = (bf16_t*)(ws + 3 * NH * NE * 2);   // 16384*64 bf16 = 2 MB
    bf16_t* kh  = qh + (size_t)NB * NT * NH;
    bf16_t* vhT = kh + (size_t)NB * NT * NH;         // [8][64][2048] bf16 = 2 MB

    convw_kernel<<<dim3(32, 3), 256, 0, stream>>>(Wq, Wk, Wv, Wb);
    proj_kernel<<<dim3(NB * NT / 16, 3), 256, 0, stream>>>(q_in, k_in, v_in, Wb, qh, kh, vhT);
    attn_kernel<<<dim3(NB * NT / 16), 256, 0, stream>>>(qh, kh, vhT, mask, out);
}

// Round 5
// 204.200 us; speedup vs baseline: 1.2438x; 1.2438x over previous
//
#include <hip/hip_runtime.h>
#include <hip/hip_bf16.h>

#define NB 8
#define NT 2048
#define NE 1024
#define NH 64

typedef __bf16 bf16_t;
typedef __bf16 bf16x8 __attribute__((ext_vector_type(8)));
typedef float f32x4 __attribute__((ext_vector_type(4)));

#define MFMA16(a, b, c) __builtin_amdgcn_mfma_f32_16x16x32_bf16(a, b, c, 0, 0, 0)

static __device__ __forceinline__ f32x4 fzero4() {
    f32x4 z = {0.f, 0.f, 0.f, 0.f};
    return z;
}

// ---------------------------------------------------------------------------
// Kernel 0: convert W (f32) -> bf16 workspace. Wb layout: [0]=Wq, [1]=Wk, [2]=Wv
// ---------------------------------------------------------------------------
__global__ __launch_bounds__(256) void convw_kernel(
    const float* __restrict__ Wq, const float* __restrict__ Wk,
    const float* __restrict__ Wv, bf16_t* __restrict__ Wb)
{
    int src = blockIdx.y;
    const float* W = (src == 0) ? Wq : ((src == 1) ? Wk : Wv);
    int idx = (blockIdx.x * 256 + threadIdx.x) * 8;  // 32 blocks * 256 thr * 8 = 65536
    f32x4 a = *(const f32x4*)(W + idx);
    f32x4 b = *(const f32x4*)(W + idx + 4);
    bf16x8 o;
#pragma unroll
    for (int j = 0; j < 4; ++j) { o[j] = (bf16_t)a[j]; o[4 + j] = (bf16_t)b[j]; }
    *(bf16x8*)(Wb + (size_t)src * (NH * NE) + idx) = o;
}

// ---------------------------------------------------------------------------
// Kernel 1: projections, 64-row blocks + K-split-2. grid (256, 3), 512 thr
// (8 waves: 4 row-groups x 2 K-halves). Same per-block W/x traffic as R2/R3
// (W 98 MB total, x 192 MB exactly once) but 6 waves/SIMD instead of 3 --
// discriminator between fabric-BW-bound (~3 TB/s wall, no change) and
// latency-bound (expect ~2x faster). One LDS merge of the 2 K-halves.
//   y=0: qh[t][h] = q . Wq   (A = x rows, B = W)
//   y=1: kh[t][h] = k . Wk
//   y=2: vhT[b][h][t] = v . Wv (A = W, B = x -> accumulator is [h][t])
// MFMA 16x16x32 conventions (m89/m91-verified):
//   A-frag: lane holds A[row=lane&15][k=(lane>>4)*8 + j]
//   B-frag: lane holds B[k=(lane>>4)*8 + j][col=lane&15]
//   D:      col = lane&15, row = (lane>>4)*4 + reg
// ---------------------------------------------------------------------------
__global__ __launch_bounds__(512, 8) void proj_kernel(
    const float* __restrict__ q_in, const float* __restrict__ k_in,
    const float* __restrict__ v_in, const bf16_t* __restrict__ Wb,
    bf16_t* __restrict__ qh, bf16_t* __restrict__ kh, bf16_t* __restrict__ vhT)
{
    const int which = blockIdx.y;
    const int w    = threadIdx.x >> 6;   // 0..7
    const int rg   = w >> 1;             // row group 0..3
    const int ks   = w & 1;              // K half 0..1
    const int lane = threadIdx.x & 63;
    const int l15  = lane & 15;
    const int lhi  = lane >> 4;
    const int t0   = blockIdx.x * 64 + rg * 16;

    const float*  x = (which == 0) ? q_in : ((which == 1) ? k_in : v_in);
    const bf16_t* W = Wb + (size_t)which * (NH * NE);

    const int kbeg = ks * 512;
    const float*  xrow = x + (size_t)(t0 + l15) * NE + kbeg + lhi * 8;
    const bf16_t* wrow = W + (size_t)l15 * NE + kbeg + lhi * 8;

    f32x4 acc[4] = {fzero4(), fzero4(), fzero4(), fzero4()};

    if (which < 2) {
#pragma unroll
        for (int g = 0; g < 16; ++g) {
            const int k0 = g * 32;
            f32x4 xa = *(const f32x4*)(xrow + k0);
            f32x4 xb = *(const f32x4*)(xrow + k0 + 4);
            bf16x8 xf;
#pragma unroll
            for (int j = 0; j < 4; ++j) { xf[j] = (bf16_t)xa[j]; xf[4 + j] = (bf16_t)xb[j]; }
#pragma unroll
            for (int cg = 0; cg < 4; ++cg) {
                bf16x8 bfw = *(const bf16x8*)(wrow + (size_t)cg * 16 * NE + k0);
                acc[cg] = MFMA16(xf, bfw, acc[cg]);
            }
        }
    } else {
#pragma unroll
        for (int g = 0; g < 16; ++g) {
            const int k0 = g * 32;
            f32x4 xa = *(const f32x4*)(xrow + k0);
            f32x4 xb = *(const f32x4*)(xrow + k0 + 4);
            bf16x8 xf;
#pragma unroll
            for (int j = 0; j < 4; ++j) { xf[j] = (bf16_t)xa[j]; xf[4 + j] = (bf16_t)xb[j]; }
#pragma unroll
            for (int hg = 0; hg < 4; ++hg) {
                bf16x8 afw = *(const bf16x8*)(wrow + (size_t)hg * 16 * NE + k0);
                acc[hg] = MFMA16(afw, xf, acc[hg]);
            }
        }
    }

    // ---- merge the 2 K-halves through LDS (ks=1 writes, ks=0 adds+stores)
    __shared__ float sm[4][16][65];

    if (which < 2) {
        if (ks == 1) {
#pragma unroll
            for (int cg = 0; cg < 4; ++cg)
#pragma unroll
                for (int r = 0; r < 4; ++r)
                    sm[rg][lhi * 4 + r][cg * 16 + l15] = acc[cg][r];
        }
        __syncthreads();
        if (ks == 0) {
            bf16_t* outp = (which == 0) ? qh : kh;
#pragma unroll
            for (int cg = 0; cg < 4; ++cg)
#pragma unroll
                for (int r = 0; r < 4; ++r) {
                    float v = acc[cg][r] + sm[rg][lhi * 4 + r][cg * 16 + l15];
                    outp[(size_t)(t0 + lhi * 4 + r) * NH + cg * 16 + l15] = (bf16_t)v;
                }
        }
    } else {
        if (ks == 1) {
#pragma unroll
            for (int hg = 0; hg < 4; ++hg)
#pragma unroll
                for (int r = 0; r < 4; ++r)
                    sm[rg][l15][hg * 16 + lhi * 4 + r] = acc[hg][r];
        }
        __syncthreads();
        if (ks == 0) {
            const int b  = t0 >> 11;
            const int tt = (t0 & 2047) + l15;
#pragma unroll
            for (int hg = 0; hg < 4; ++hg)
#pragma unroll
                for (int r = 0; r < 4; ++r) {
                    int h = hg * 16 + lhi * 4 + r;
                    float v = acc[hg][r] + sm[rg][l15][h];
                    vhT[(((size_t)(b * NH + h)) << 11) + tt] = (bf16_t)v;
                }
        }
    }
}

// ---------------------------------------------------------------------------
// Kernel 2: split-K flash attention, causal + key-mask.
// grid = (B*T/16) linear blocks, 256 thr. Block owns ONE 16-row q-tile; its
// 4 waves split the causal key range 4 ways (64-key tiles each), then merge
// partial (m, l, O) through LDS.
// ---------------------------------------------------------------------------
__global__ __launch_bounds__(256) void attn_kernel(
    const bf16_t* __restrict__ qh, const bf16_t* __restrict__ kh,
    const bf16_t* __restrict__ vhT, const int* __restrict__ mask,
    float* __restrict__ out)
{
    const int lin  = blockIdx.x;
    const int qt16 = lin >> 3;     // 0..127: q-tile (16 rows)
    const int b    = lin & 7;
    const int w    = threadIdx.x >> 6;   // key-split index 0..3
    const int lane = threadIdx.x & 63;
    const int l15  = lane & 15;
    const int lhi  = lane >> 4;

    __shared__ __align__(16) char plds[4][2][2048];   // [wave][dbuf][16x64 bf16]
    __shared__ float sm_o[4][16][65];                  // [wave][row][col] (+1 pad)
    __shared__ float sm_ml[4][2][16];                  // [wave][m/l][row]

    const int q0  = qt16 * 16;
    const int nkt = (q0 + 15) / 64 + 1;     // causal 64-key tiles
    const int len = (nkt + 3) >> 2;         // ceil(nkt/4)
    const int kt_beg = w * len;
    const int kt_end = min(kt_beg + len, nkt);

    // Q fragments (H=64 -> two k-chunks of 32)
    const bf16_t* qbase = qh + (size_t)(b * NT + q0 + l15) * NH + lhi * 8;
    bf16x8 qf0 = *(const bf16x8*)(qbase);
    bf16x8 qf1 = *(const bf16x8*)(qbase + 32);

    f32x4 acc_o[4] = {fzero4(), fzero4(), fzero4(), fzero4()};
    float m[4]    = {-1e30f, -1e30f, -1e30f, -1e30f};
    float lsum[4] = {0.f, 0.f, 0.f, 0.f};

    const int qq0 = q0 + lhi * 4;  // this lane's first q-row

    for (int kt = kt_beg; kt < kt_end; ++kt) {
        // ---- S = (qh . kh^T) * 0.125, tile 16q x 64k --------------------
        const bf16_t* kbase = kh + (size_t)(b * NT + kt * 64 + l15) * NH + lhi * 8;
        f32x4 s[4] = {fzero4(), fzero4(), fzero4(), fzero4()};
#pragma unroll
        for (int cg = 0; cg < 4; ++cg) {
            bf16x8 kf0 = *(const bf16x8*)(kbase + (size_t)cg * 16 * NH);
            bf16x8 kf1 = *(const bf16x8*)(kbase + (size_t)cg * 16 * NH + 32);
            s[cg] = MFMA16(qf0, kf0, s[cg]);
            s[cg] = MFMA16(qf1, kf1, s[cg]);
        }

        // ---- mask + scale ----------------------------------------------
        int mk[4];
#pragma unroll
        for (int cg = 0; cg < 4; ++cg) mk[cg] = mask[b * NT + kt * 64 + cg * 16 + l15];
#pragma unroll
        for (int cg = 0; cg < 4; ++cg) {
            int kk = kt * 64 + cg * 16 + l15;
#pragma unroll
            for (int r = 0; r < 4; ++r) {
                float sv = s[cg][r] * 0.125f;
                bool ok = (kk <= qq0 + r) && (mk[cg] != 0);
                s[cg][r] = ok ? sv : -1e30f;
            }
        }

        // ---- online softmax (row spread over 16 lanes x 4 cgs) ----------
        float mx[4];
#pragma unroll
        for (int r = 0; r < 4; ++r) {
            mx[r] = fmaxf(fmaxf(s[0][r], s[1][r]), fmaxf(s[2][r], s[3][r]));
#pragma unroll
            for (int d = 1; d < 16; d <<= 1) mx[r] = fmaxf(mx[r], __shfl_xor(mx[r], d));
        }
        float resc[4];
#pragma unroll
        for (int r = 0; r < 4; ++r) {
            float mn = fmaxf(m[r], mx[r]);
            resc[r] = __expf(m[r] - mn);
            m[r] = mn;
        }
        float rs[4] = {0.f, 0.f, 0.f, 0.f};
#pragma unroll
        for (int cg = 0; cg < 4; ++cg)
#pragma unroll
            for (int r = 0; r < 4; ++r) {
                float sv = s[cg][r];
                float p = (sv > -5e29f) ? __expf(sv - m[r]) : 0.f;  // masked -> exactly 0
                s[cg][r] = p;
                rs[r] += p;
            }
#pragma unroll
        for (int r = 0; r < 4; ++r) {
#pragma unroll
            for (int d = 1; d < 16; d <<= 1) rs[r] += __shfl_xor(rs[r], d);
            lsum[r] = lsum[r] * resc[r] + rs[r];
        }
#pragma unroll
        for (int cg = 0; cg < 4; ++cg)
#pragma unroll
            for (int r = 0; r < 4; ++r) acc_o[cg][r] *= resc[r];

        // ---- P -> LDS (bf16, XOR swizzle: byte ^= (row&7)<<4) -----------
        char* pb = &plds[w][kt & 1][0];
#pragma unroll
        for (int cg = 0; cg < 4; ++cg)
#pragma unroll
            for (int r = 0; r < 4; ++r) {
                int row = lhi * 4 + r;
                int col = cg * 16 + l15;
                int byte = (row * 128 + col * 2) ^ ((row & 7) << 4);
                *(bf16_t*)(pb + byte) = (bf16_t)s[cg][r];
            }

        // ---- O += P . V  (A-frags from LDS, B-frags from vhT, contiguous)
        const bf16_t* vbase = vhT + ((size_t)(b * NH + l15) << 11) + kt * 64 + lhi * 8;
#pragma unroll
        for (int kc = 0; kc < 2; ++kc) {
            int row = l15;
            int byte = (row * 128 + kc * 64 + lhi * 16) ^ ((row & 7) << 4);
            bf16x8 pf = *(bf16x8*)(pb + byte);
#pragma unroll
            for (int cg = 0; cg < 4; ++cg) {
                bf16x8 vf = *(const bf16x8*)(vbase + ((size_t)cg * 16 << 11) + kc * 32);
                acc_o[cg] = MFMA16(pf, vf, acc_o[cg]);
            }
        }
    }

    // ---- write this wave's partials to LDS ------------------------------
#pragma unroll
    for (int cg = 0; cg < 4; ++cg)
#pragma unroll
        for (int r = 0; r < 4; ++r)
            sm_o[w][lhi * 4 + r][cg * 16 + l15] = acc_o[cg][r];
    if (l15 == 0) {
#pragma unroll
        for (int r = 0; r < 4; ++r) {
            sm_ml[w][0][lhi * 4 + r] = m[r];
            sm_ml[w][1][lhi * 4 + r] = lsum[r];
        }
    }
    __syncthreads();

    // ---- merge 4 splits; this thread covers col = w*16+l15, rows lhi*4+r
#pragma unroll
    for (int r = 0; r < 4; ++r) {
        int row = lhi * 4 + r;
        float mg = -1e30f;
#pragma unroll
        for (int s = 0; s < 4; ++s) mg = fmaxf(mg, sm_ml[s][0][row]);
        float lg = 0.f, og = 0.f;
#pragma unroll
        for (int s = 0; s < 4; ++s) {
            float e = __expf(sm_ml[s][0][row] - mg);
            lg += e * sm_ml[s][1][row];
            og += e * sm_o[s][row][w * 16 + l15];
        }
        out[(size_t)(b * NT + q0 + row) * NH + w * 16 + l15] = og / lg;
    }
}

// ---------------------------------------------------------------------------
extern "C" void kernel_launch(void* const* d_in, const int* in_sizes, int n_in,
                              void* d_out, int out_size, void* d_ws, size_t ws_size,
                              hipStream_t stream)
{
    const float* k_in = (const float*)d_in[0];
    const float* q_in = (const float*)d_in[1];
    const float* v_in = (const float*)d_in[2];
    const int*   mask = (const int*)d_in[3];
    const float* Wk   = (const float*)d_in[4];
    const float* Wq   = (const float*)d_in[5];
    const float* Wv   = (const float*)d_in[6];
    float* out = (float*)d_out;

    char* ws = (char*)d_ws;
    bf16_t* Wb  = (bf16_t*)ws;                       // 3*64*1024 bf16 = 384 KB
    bf16_t* qh  = (bf16_t*)(ws + 3 * NH * NE * 2);   // 16384*64 bf16 = 2 MB
    bf16_t* kh  = qh + (size_t)NB * NT * NH;
    bf16_t* vhT = kh + (size_t)NB * NT * NH;         // [8][64][2048] bf16 = 2 MB

    convw_kernel<<<dim3(32, 3), 256, 0, stream>>>(Wq, Wk, Wv, Wb);
    proj_kernel<<<dim3(NB * NT / 64, 3), 512, 0, stream>>>(q_in, k_in, v_in, Wb, qh, kh, vhT);
    attn_kernel<<<dim3(NB * NT / 16), 256, 0, stream>>>(qh, kh, vhT, mask, out);
}

// Round 6
// 124.946 us; speedup vs baseline: 2.0327x; 1.6343x over previous
//
#include <hip/hip_runtime.h>
#include <hip/hip_bf16.h>

#define NB 8
#define NT 2048
#define NE 1024
#define NH 64

typedef __bf16 bf16_t;
typedef __bf16 bf16x8 __attribute__((ext_vector_type(8)));
typedef float f32x4 __attribute__((ext_vector_type(4)));

#define MFMA16(a, b, c) __builtin_amdgcn_mfma_f32_16x16x32_bf16(a, b, c, 0, 0, 0)

static __device__ __forceinline__ f32x4 fzero4() {
    f32x4 z = {0.f, 0.f, 0.f, 0.f};
    return z;
}

// ---------------------------------------------------------------------------
// Kernel 0: convert W (f32) -> bf16 workspace. Wb layout: [0]=Wq, [1]=Wk, [2]=Wv
// ---------------------------------------------------------------------------
__global__ __launch_bounds__(256) void convw_kernel(
    const float* __restrict__ Wq, const float* __restrict__ Wk,
    const float* __restrict__ Wv, bf16_t* __restrict__ Wb)
{
    int src = blockIdx.y;
    const float* W = (src == 0) ? Wq : ((src == 1) ? Wk : Wv);
    int idx = (blockIdx.x * 256 + threadIdx.x) * 8;  // 32 blocks * 256 thr * 8 = 65536
    f32x4 a = *(const f32x4*)(W + idx);
    f32x4 b = *(const f32x4*)(W + idx + 4);
    bf16x8 o;
#pragma unroll
    for (int j = 0; j < 4; ++j) { o[j] = (bf16_t)a[j]; o[4 + j] = (bf16_t)b[j]; }
    *(bf16x8*)(Wb + (size_t)src * (NH * NE) + idx) = o;
}

// ---------------------------------------------------------------------------
// Kernel 1: projections, 64-row blocks + K-split-2. grid (256, 3), 512 thr
// (8 waves: 4 row-groups x 2 K-halves).
// R6 change vs R5: __launch_bounds__(512) WITHOUT the ",8" min-waves arg.
// The ",8" capped the allocator at 64 VGPR; it chose 32 WITH scratch spills
// -> 200-370 MB of spill HBM traffic (R4/R5 WRITE_SIZE explosion). At the
// natural ~44-56 VGPR (<=64) hardware still allows 8 waves/SIMD, so the
// bound bought nothing. Grid supplies 24 waves/CU (6/SIMD), 2x R3's TLP.
//   y=0: qh[t][h] = q . Wq   (A = x rows, B = W)
//   y=1: kh[t][h] = k . Wk
//   y=2: vhT[b][h][t] = v . Wv (A = W, B = x -> accumulator is [h][t])
// MFMA 16x16x32 conventions (m89/m91-verified):
//   A-frag: lane holds A[row=lane&15][k=(lane>>4)*8 + j]
//   B-frag: lane holds B[k=(lane>>4)*8 + j][col=lane&15]
//   D:      col = lane&15, row = (lane>>4)*4 + reg
// ---------------------------------------------------------------------------
__global__ __launch_bounds__(512) void proj_kernel(
    const float* __restrict__ q_in, const float* __restrict__ k_in,
    const float* __restrict__ v_in, const bf16_t* __restrict__ Wb,
    bf16_t* __restrict__ qh, bf16_t* __restrict__ kh, bf16_t* __restrict__ vhT)
{
    const int which = blockIdx.y;
    const int w    = threadIdx.x >> 6;   // 0..7
    const int rg   = w >> 1;             // row group 0..3
    const int ks   = w & 1;              // K half 0..1
    const int lane = threadIdx.x & 63;
    const int l15  = lane & 15;
    const int lhi  = lane >> 4;
    const int t0   = blockIdx.x * 64 + rg * 16;

    const float*  x = (which == 0) ? q_in : ((which == 1) ? k_in : v_in);
    const bf16_t* W = Wb + (size_t)which * (NH * NE);

    const int kbeg = ks * 512;
    const float*  xrow = x + (size_t)(t0 + l15) * NE + kbeg + lhi * 8;
    const bf16_t* wrow = W + (size_t)l15 * NE + kbeg + lhi * 8;

    f32x4 acc[4] = {fzero4(), fzero4(), fzero4(), fzero4()};

    if (which < 2) {
#pragma unroll
        for (int g = 0; g < 16; ++g) {
            const int k0 = g * 32;
            f32x4 xa = *(const f32x4*)(xrow + k0);
            f32x4 xb = *(const f32x4*)(xrow + k0 + 4);
            bf16x8 xf;
#pragma unroll
            for (int j = 0; j < 4; ++j) { xf[j] = (bf16_t)xa[j]; xf[4 + j] = (bf16_t)xb[j]; }
#pragma unroll
            for (int cg = 0; cg < 4; ++cg) {
                bf16x8 bfw = *(const bf16x8*)(wrow + (size_t)cg * 16 * NE + k0);
                acc[cg] = MFMA16(xf, bfw, acc[cg]);
            }
        }
    } else {
#pragma unroll
        for (int g = 0; g < 16; ++g) {
            const int k0 = g * 32;
            f32x4 xa = *(const f32x4*)(xrow + k0);
            f32x4 xb = *(const f32x4*)(xrow + k0 + 4);
            bf16x8 xf;
#pragma unroll
            for (int j = 0; j < 4; ++j) { xf[j] = (bf16_t)xa[j]; xf[4 + j] = (bf16_t)xb[j]; }
#pragma unroll
            for (int hg = 0; hg < 4; ++hg) {
                bf16x8 afw = *(const bf16x8*)(wrow + (size_t)hg * 16 * NE + k0);
                acc[hg] = MFMA16(afw, xf, acc[hg]);
            }
        }
    }

    // ---- merge the 2 K-halves through LDS (ks=1 writes, ks=0 adds+stores)
    __shared__ float sm[4][16][65];

    if (which < 2) {
        if (ks == 1) {
#pragma unroll
            for (int cg = 0; cg < 4; ++cg)
#pragma unroll
                for (int r = 0; r < 4; ++r)
                    sm[rg][lhi * 4 + r][cg * 16 + l15] = acc[cg][r];
        }
        __syncthreads();
        if (ks == 0) {
            bf16_t* outp = (which == 0) ? qh : kh;
#pragma unroll
            for (int cg = 0; cg < 4; ++cg)
#pragma unroll
                for (int r = 0; r < 4; ++r) {
                    float v = acc[cg][r] + sm[rg][lhi * 4 + r][cg * 16 + l15];
                    outp[(size_t)(t0 + lhi * 4 + r) * NH + cg * 16 + l15] = (bf16_t)v;
                }
        }
    } else {
        if (ks == 1) {
#pragma unroll
            for (int hg = 0; hg < 4; ++hg)
#pragma unroll
                for (int r = 0; r < 4; ++r)
                    sm[rg][l15][hg * 16 + lhi * 4 + r] = acc[hg][r];
        }
        __syncthreads();
        if (ks == 0) {
            const int b  = t0 >> 11;
            const int tt = (t0 & 2047) + l15;
#pragma unroll
            for (int hg = 0; hg < 4; ++hg)
#pragma unroll
                for (int r = 0; r < 4; ++r) {
                    int h = hg * 16 + lhi * 4 + r;
                    float v = acc[hg][r] + sm[rg][l15][h];
                    vhT[(((size_t)(b * NH + h)) << 11) + tt] = (bf16_t)v;
                }
        }
    }
}

// ---------------------------------------------------------------------------
// Kernel 2: split-K flash attention, causal + key-mask.
// grid = (B*T/16) linear blocks, 256 thr. Block owns ONE 16-row q-tile; its
// 4 waves split the causal key range 4 ways (64-key tiles each), then merge
// partial (m, l, O) through LDS.
// ---------------------------------------------------------------------------
__global__ __launch_bounds__(256) void attn_kernel(
    const bf16_t* __restrict__ qh, const bf16_t* __restrict__ kh,
    const bf16_t* __restrict__ vhT, const int* __restrict__ mask,
    float* __restrict__ out)
{
    const int lin  = blockIdx.x;
    const int qt16 = lin >> 3;     // 0..127: q-tile (16 rows)
    const int b    = lin & 7;
    const int w    = threadIdx.x >> 6;   // key-split index 0..3
    const int lane = threadIdx.x & 63;
    const int l15  = lane & 15;
    const int lhi  = lane >> 4;

    __shared__ __align__(16) char plds[4][2][2048];   // [wave][dbuf][16x64 bf16]
    __shared__ float sm_o[4][16][65];                  // [wave][row][col] (+1 pad)
    __shared__ float sm_ml[4][2][16];                  // [wave][m/l][row]

    const int q0  = qt16 * 16;
    const int nkt = (q0 + 15) / 64 + 1;     // causal 64-key tiles
    const int len = (nkt + 3) >> 2;         // ceil(nkt/4)
    const int kt_beg = w * len;
    const int kt_end = min(kt_beg + len, nkt);

    // Q fragments (H=64 -> two k-chunks of 32)
    const bf16_t* qbase = qh + (size_t)(b * NT + q0 + l15) * NH + lhi * 8;
    bf16x8 qf0 = *(const bf16x8*)(qbase);
    bf16x8 qf1 = *(const bf16x8*)(qbase + 32);

    f32x4 acc_o[4] = {fzero4(), fzero4(), fzero4(), fzero4()};
    float m[4]    = {-1e30f, -1e30f, -1e30f, -1e30f};
    float lsum[4] = {0.f, 0.f, 0.f, 0.f};

    const int qq0 = q0 + lhi * 4;  // this lane's first q-row

    for (int kt = kt_beg; kt < kt_end; ++kt) {
        // ---- S = (qh . kh^T) * 0.125, tile 16q x 64k --------------------
        const bf16_t* kbase = kh + (size_t)(b * NT + kt * 64 + l15) * NH + lhi * 8;
        f32x4 s[4] = {fzero4(), fzero4(), fzero4(), fzero4()};
#pragma unroll
        for (int cg = 0; cg < 4; ++cg) {
            bf16x8 kf0 = *(const bf16x8*)(kbase + (size_t)cg * 16 * NH);
            bf16x8 kf1 = *(const bf16x8*)(kbase + (size_t)cg * 16 * NH + 32);
            s[cg] = MFMA16(qf0, kf0, s[cg]);
            s[cg] = MFMA16(qf1, kf1, s[cg]);
        }

        // ---- mask + scale ----------------------------------------------
        int mk[4];
#pragma unroll
        for (int cg = 0; cg < 4; ++cg) mk[cg] = mask[b * NT + kt * 64 + cg * 16 + l15];
#pragma unroll
        for (int cg = 0; cg < 4; ++cg) {
            int kk = kt * 64 + cg * 16 + l15;
#pragma unroll
            for (int r = 0; r < 4; ++r) {
                float sv = s[cg][r] * 0.125f;
                bool ok = (kk <= qq0 + r) && (mk[cg] != 0);
                s[cg][r] = ok ? sv : -1e30f;
            }
        }

        // ---- online softmax (row spread over 16 lanes x 4 cgs) ----------
        float mx[4];
#pragma unroll
        for (int r = 0; r < 4; ++r) {
            mx[r] = fmaxf(fmaxf(s[0][r], s[1][r]), fmaxf(s[2][r], s[3][r]));
#pragma unroll
            for (int d = 1; d < 16; d <<= 1) mx[r] = fmaxf(mx[r], __shfl_xor(mx[r], d));
        }
        float resc[4];
#pragma unroll
        for (int r = 0; r < 4; ++r) {
            float mn = fmaxf(m[r], mx[r]);
            resc[r] = __expf(m[r] - mn);
            m[r] = mn;
        }
        float rs[4] = {0.f, 0.f, 0.f, 0.f};
#pragma unroll
        for (int cg = 0; cg < 4; ++cg)
#pragma unroll
            for (int r = 0; r < 4; ++r) {
                float sv = s[cg][r];
                float p = (sv > -5e29f) ? __expf(sv - m[r]) : 0.f;  // masked -> exactly 0
                s[cg][r] = p;
                rs[r] += p;
            }
#pragma unroll
        for (int r = 0; r < 4; ++r) {
#pragma unroll
            for (int d = 1; d < 16; d <<= 1) rs[r] += __shfl_xor(rs[r], d);
            lsum[r] = lsum[r] * resc[r] + rs[r];
        }
#pragma unroll
        for (int cg = 0; cg < 4; ++cg)
#pragma unroll
            for (int r = 0; r < 4; ++r) acc_o[cg][r] *= resc[r];

        // ---- P -> LDS (bf16, XOR swizzle: byte ^= (row&7)<<4) -----------
        char* pb = &plds[w][kt & 1][0];
#pragma unroll
        for (int cg = 0; cg < 4; ++cg)
#pragma unroll
            for (int r = 0; r < 4; ++r) {
                int row = lhi * 4 + r;
                int col = cg * 16 + l15;
                int byte = (row * 128 + col * 2) ^ ((row & 7) << 4);
                *(bf16_t*)(pb + byte) = (bf16_t)s[cg][r];
            }

        // ---- O += P . V  (A-frags from LDS, B-frags from vhT, contiguous)
        const bf16_t* vbase = vhT + ((size_t)(b * NH + l15) << 11) + kt * 64 + lhi * 8;
#pragma unroll
        for (int kc = 0; kc < 2; ++kc) {
            int row = l15;
            int byte = (row * 128 + kc * 64 + lhi * 16) ^ ((row & 7) << 4);
            bf16x8 pf = *(bf16x8*)(pb + byte);
#pragma unroll
            for (int cg = 0; cg < 4; ++cg) {
                bf16x8 vf = *(const bf16x8*)(vbase + ((size_t)cg * 16 << 11) + kc * 32);
                acc_o[cg] = MFMA16(pf, vf, acc_o[cg]);
            }
        }
    }

    // ---- write this wave's partials to LDS ------------------------------
#pragma unroll
    for (int cg = 0; cg < 4; ++cg)
#pragma unroll
        for (int r = 0; r < 4; ++r)
            sm_o[w][lhi * 4 + r][cg * 16 + l15] = acc_o[cg][r];
    if (l15 == 0) {
#pragma unroll
        for (int r = 0; r < 4; ++r) {
            sm_ml[w][0][lhi * 4 + r] = m[r];
            sm_ml[w][1][lhi * 4 + r] = lsum[r];
        }
    }
    __syncthreads();

    // ---- merge 4 splits; this thread covers col = w*16+l15, rows lhi*4+r
#pragma unroll
    for (int r = 0; r < 4; ++r) {
        int row = lhi * 4 + r;
        float mg = -1e30f;
#pragma unroll
        for (int s = 0; s < 4; ++s) mg = fmaxf(mg, sm_ml[s][0][row]);
        float lg = 0.f, og = 0.f;
#pragma unroll
        for (int s = 0; s < 4; ++s) {
            float e = __expf(sm_ml[s][0][row] - mg);
            lg += e * sm_ml[s][1][row];
            og += e * sm_o[s][row][w * 16 + l15];
        }
        out[(size_t)(b * NT + q0 + row) * NH + w * 16 + l15] = og / lg;
    }
}

// ---------------------------------------------------------------------------
extern "C" void kernel_launch(void* const* d_in, const int* in_sizes, int n_in,
                              void* d_out, int out_size, void* d_ws, size_t ws_size,
                              hipStream_t stream)
{
    const float* k_in = (const float*)d_in[0];
    const float* q_in = (const float*)d_in[1];
    const float* v_in = (const float*)d_in[2];
    const int*   mask = (const int*)d_in[3];
    const float* Wk   = (const float*)d_in[4];
    const float* Wq   = (const float*)d_in[5];
    const float* Wv   = (const float*)d_in[6];
    float* out = (float*)d_out;

    char* ws = (char*)d_ws;
    bf16_t* Wb  = (bf16_t*)ws;                       // 3*64*1024 bf16 = 384 KB
    bf16_t* qh  = (bf16_t*)(ws + 3 * NH * NE * 2);   // 16384*64 bf16 = 2 MB
    bf16_t* kh  = qh + (size_t)NB * NT * NH;
    bf16_t* vhT = kh + (size_t)NB * NT * NH;         // [8][64][2048] bf16 = 2 MB

    convw_kernel<<<dim3(32, 3), 256, 0, stream>>>(Wq, Wk, Wv, Wb);
    proj_kernel<<<dim3(NB * NT / 64, 3), 512, 0, stream>>>(q_in, k_in, v_in, Wb, qh, kh, vhT);
    attn_kernel<<<dim3(NB * NT / 16), 256, 0, stream>>>(qh, kh, vhT, mask, out);
}

// Round 7
// 84.948 us; speedup vs baseline: 2.9899x; 1.4709x over previous
//
#include <hip/hip_runtime.h>
#include <hip/hip_bf16.h>

#define NB 8
#define NT 2048
#define NE 1024
#define NH 64

typedef __bf16 bf16_t;
typedef __bf16 bf16x8 __attribute__((ext_vector_type(8)));
typedef float f32x4 __attribute__((ext_vector_type(4)));

#define MFMA16(a, b, c) __builtin_amdgcn_mfma_f32_16x16x32_bf16(a, b, c, 0, 0, 0)

static __device__ __forceinline__ f32x4 fzero4() {
    f32x4 z = {0.f, 0.f, 0.f, 0.f};
    return z;
}

// async global -> LDS, 16 B per lane. LDS dest is wave-uniform base + lane*16
// (HW rule, m104/m108); global src is per-lane (pre-swizzle goes on the src).
static __device__ __forceinline__ void gload_lds16(const void* gsrc, void* ldst) {
    __builtin_amdgcn_global_load_lds(
        (const __attribute__((address_space(1))) char*)gsrc,
        (__attribute__((address_space(3))) char*)ldst, 16, 0, 0);
}

// ---------------------------------------------------------------------------
// Kernel 0: convert W (f32) -> bf16 workspace. Wb layout: [0]=Wq, [1]=Wk, [2]=Wv
// ---------------------------------------------------------------------------
__global__ __launch_bounds__(256) void convw_kernel(
    const float* __restrict__ Wq, const float* __restrict__ Wk,
    const float* __restrict__ Wv, bf16_t* __restrict__ Wb)
{
    int src = blockIdx.y;
    const float* W = (src == 0) ? Wq : ((src == 1) ? Wk : Wv);
    int idx = (blockIdx.x * 256 + threadIdx.x) * 8;  // 32 blocks * 256 thr * 8 = 65536
    f32x4 a = *(const f32x4*)(W + idx);
    f32x4 b = *(const f32x4*)(W + idx + 4);
    bf16x8 o;
#pragma unroll
    for (int j = 0; j < 4; ++j) { o[j] = (bf16_t)a[j]; o[4 + j] = (bf16_t)b[j]; }
    *(bf16x8*)(Wb + (size_t)src * (NH * NE) + idx) = o;
}

// ---------------------------------------------------------------------------
// Kernel 1: projections via global_load_lds double-buffered staging (m97
// structure). grid (256, 3), 256 thr (4 waves, 16 t-rows each). K-loop: 16
// steps of BK=64. Per step: stage x[64][64]f32 (16 KB, 4 issues/wave) and
// W[64][64]bf16 (8 KB, 2 issues/wave) into buf^1 while computing buf.
// LDS layout is chunk-linear with XOR-of-row swizzle applied to the GLOBAL
// source (G21/m173): x chunk (row, phys) holds global chunk phys^(row&15);
// W chunk (row, phys) holds phys^(row&7). Fragment ds_reads then hit
// 2-way-max bank aliasing (free, m136).
//   y=0: qh[t][h] = q . Wq   (A = x rows, B = W)
//   y=1: kh[t][h] = k . Wk
//   y=2: vhT[b][h][t] = v . Wv (A = W, B = x -> accumulator is [h][t])
// MFMA 16x16x32 conventions (m89/m91-verified):
//   A-frag: lane holds A[row=lane&15][k=(lane>>4)*8 + j]
//   B-frag: lane holds B[k=(lane>>4)*8 + j][col=lane&15]
//   D:      col = lane&15, row = (lane>>4)*4 + reg
// ---------------------------------------------------------------------------
__global__ __launch_bounds__(256) void proj_kernel(
    const float* __restrict__ q_in, const float* __restrict__ k_in,
    const float* __restrict__ v_in, const bf16_t* __restrict__ Wb,
    bf16_t* __restrict__ qh, bf16_t* __restrict__ kh, bf16_t* __restrict__ vhT)
{
    const int which = blockIdx.y;
    const int w    = threadIdx.x >> 6;   // wave 0..3, owns t-rows w*16..w*16+15
    const int lane = threadIdx.x & 63;
    const int l15  = lane & 15;
    const int lhi  = lane >> 4;
    const int t0   = blockIdx.x * 64;

    const float*  x = (which == 0) ? q_in : ((which == 1) ? k_in : v_in);
    const bf16_t* W = Wb + (size_t)which * (NH * NE);

    __shared__ __align__(16) char xlds[2][16384];   // [buf][64 rows][16 chunks][16B]
    __shared__ __align__(16) char wlds[2][8192];    // [buf][64 rows][ 8 chunks][16B]

    // ---- staging source pointers (per-lane, swizzled; step adds k0) -----
    const float* xsrc[4];
#pragma unroll
    for (int i = 0; i < 4; ++i) {
        int cid = (w * 4 + i) * 64 + lane;          // 0..1023
        int row = cid >> 4, phys = cid & 15;
        int logical = phys ^ (row & 15);
        xsrc[i] = x + (size_t)(t0 + row) * NE + logical * 4;
    }
    const bf16_t* wsrc[2];
#pragma unroll
    for (int i = 0; i < 2; ++i) {
        int cid = (w * 2 + i) * 64 + lane;          // 0..511
        int row = cid >> 3, phys = cid & 7;
        int logical = phys ^ (row & 7);
        wsrc[i] = W + (size_t)row * NE + logical * 8;
    }

    // ---- fragment read offsets (step-invariant byte offsets in a buffer) -
    const int xrow = w * 16 + l15;                  // this lane's t-row (A) / col (B)
    int xoff[2][2];                                 // [kk][j]: 16B chunk of 4 f32
#pragma unroll
    for (int kk = 0; kk < 2; ++kk)
#pragma unroll
        for (int j = 0; j < 2; ++j) {
            int c = kk * 8 + lhi * 2 + j;
            xoff[kk][j] = (xrow * 16 + (c ^ (xrow & 15))) * 16;
        }
    int woff[2][4];                                 // [kk][cg]: 16B chunk of 8 bf16
#pragma unroll
    for (int kk = 0; kk < 2; ++kk)
#pragma unroll
        for (int cg = 0; cg < 4; ++cg) {
            int wr = cg * 16 + l15;
            woff[kk][cg] = (wr * 8 + ((kk * 4 + lhi) ^ (wr & 7))) * 16;
        }

    f32x4 acc[4] = {fzero4(), fzero4(), fzero4(), fzero4()};

    // ---- prologue: stage tile 0 ------------------------------------------
#pragma unroll
    for (int i = 0; i < 4; ++i) gload_lds16(xsrc[i], &xlds[0][(w * 4 + i) * 1024]);
#pragma unroll
    for (int i = 0; i < 2; ++i) gload_lds16(wsrc[i], &wlds[0][(w * 2 + i) * 1024]);
    __syncthreads();

    // ---- main loop: stage next, compute current, drain+barrier ----------
#pragma unroll
    for (int step = 0; step < 16; ++step) {
        const int cur = step & 1;
        if (step < 15) {
            const int k0 = (step + 1) * 64;
#pragma unroll
            for (int i = 0; i < 4; ++i)
                gload_lds16(xsrc[i] + k0, &xlds[cur ^ 1][(w * 4 + i) * 1024]);
#pragma unroll
            for (int i = 0; i < 2; ++i)
                gload_lds16(wsrc[i] + k0, &wlds[cur ^ 1][(w * 2 + i) * 1024]);
        }
        const char* xb = xlds[cur];
        const char* wb = wlds[cur];
#pragma unroll
        for (int kk = 0; kk < 2; ++kk) {
            f32x4 a0 = *(const f32x4*)(xb + xoff[kk][0]);
            f32x4 a1 = *(const f32x4*)(xb + xoff[kk][1]);
            bf16x8 xf;
#pragma unroll
            for (int j = 0; j < 4; ++j) { xf[j] = (bf16_t)a0[j]; xf[4 + j] = (bf16_t)a1[j]; }
            if (which < 2) {
#pragma unroll
                for (int cg = 0; cg < 4; ++cg) {
                    bf16x8 wf = *(const bf16x8*)(wb + woff[kk][cg]);
                    acc[cg] = MFMA16(xf, wf, acc[cg]);
                }
            } else {
#pragma unroll
                for (int hg = 0; hg < 4; ++hg) {
                    bf16x8 wf = *(const bf16x8*)(wb + woff[kk][hg]);
                    acc[hg] = MFMA16(wf, xf, acc[hg]);
                }
            }
        }
        __syncthreads();   // drains vmcnt(0): next buffer is ready
    }

    // ---- epilogue --------------------------------------------------------
    if (which < 2) {
        bf16_t* outp = (which == 0) ? qh : kh;
#pragma unroll
        for (int cg = 0; cg < 4; ++cg)
#pragma unroll
            for (int r = 0; r < 4; ++r) {
                int t = t0 + w * 16 + lhi * 4 + r;
                outp[(size_t)t * NH + cg * 16 + l15] = (bf16_t)acc[cg][r];
            }
    } else {
        const int tg = t0 + w * 16 + l15;
        const int b  = tg >> 11;
        const int tt = tg & 2047;
#pragma unroll
        for (int hg = 0; hg < 4; ++hg)
#pragma unroll
            for (int r = 0; r < 4; ++r) {
                int h = hg * 16 + lhi * 4 + r;
                vhT[(((size_t)(b * NH + h)) << 11) + tt] = (bf16_t)acc[hg][r];
            }
    }
}

// ---------------------------------------------------------------------------
// Kernel 2: split-K flash attention, causal + key-mask.
// grid = (B*T/16) linear blocks, 256 thr. Block owns ONE 16-row q-tile; its
// 4 waves split the causal key range 4 ways (64-key tiles each), then merge
// partial (m, l, O) through LDS.
// ---------------------------------------------------------------------------
__global__ __launch_bounds__(256) void attn_kernel(
    const bf16_t* __restrict__ qh, const bf16_t* __restrict__ kh,
    const bf16_t* __restrict__ vhT, const int* __restrict__ mask,
    float* __restrict__ out)
{
    const int lin  = blockIdx.x;
    const int qt16 = lin >> 3;     // 0..127: q-tile (16 rows)
    const int b    = lin & 7;
    const int w    = threadIdx.x >> 6;   // key-split index 0..3
    const int lane = threadIdx.x & 63;
    const int l15  = lane & 15;
    const int lhi  = lane >> 4;

    __shared__ __align__(16) char plds[4][2][2048];   // [wave][dbuf][16x64 bf16]
    __shared__ float sm_o[4][16][65];                  // [wave][row][col] (+1 pad)
    __shared__ float sm_ml[4][2][16];                  // [wave][m/l][row]

    const int q0  = qt16 * 16;
    const int nkt = (q0 + 15) / 64 + 1;     // causal 64-key tiles
    const int len = (nkt + 3) >> 2;         // ceil(nkt/4)
    const int kt_beg = w * len;
    const int kt_end = min(kt_beg + len, nkt);

    // Q fragments (H=64 -> two k-chunks of 32)
    const bf16_t* qbase = qh + (size_t)(b * NT + q0 + l15) * NH + lhi * 8;
    bf16x8 qf0 = *(const bf16x8*)(qbase);
    bf16x8 qf1 = *(const bf16x8*)(qbase + 32);

    f32x4 acc_o[4] = {fzero4(), fzero4(), fzero4(), fzero4()};
    float m[4]    = {-1e30f, -1e30f, -1e30f, -1e30f};
    float lsum[4] = {0.f, 0.f, 0.f, 0.f};

    const int qq0 = q0 + lhi * 4;  // this lane's first q-row

    for (int kt = kt_beg; kt < kt_end; ++kt) {
        // ---- S = (qh . kh^T) * 0.125, tile 16q x 64k --------------------
        const bf16_t* kbase = kh + (size_t)(b * NT + kt * 64 + l15) * NH + lhi * 8;
        f32x4 s[4] = {fzero4(), fzero4(), fzero4(), fzero4()};
#pragma unroll
        for (int cg = 0; cg < 4; ++cg) {
            bf16x8 kf0 = *(const bf16x8*)(kbase + (size_t)cg * 16 * NH);
            bf16x8 kf1 = *(const bf16x8*)(kbase + (size_t)cg * 16 * NH + 32);
            s[cg] = MFMA16(qf0, kf0, s[cg]);
            s[cg] = MFMA16(qf1, kf1, s[cg]);
        }

        // ---- mask + scale ----------------------------------------------
        int mk[4];
#pragma unroll
        for (int cg = 0; cg < 4; ++cg) mk[cg] = mask[b * NT + kt * 64 + cg * 16 + l15];
#pragma unroll
        for (int cg = 0; cg < 4; ++cg) {
            int kk = kt * 64 + cg * 16 + l15;
#pragma unroll
            for (int r = 0; r < 4; ++r) {
                float sv = s[cg][r] * 0.125f;
                bool ok = (kk <= qq0 + r) && (mk[cg] != 0);
                s[cg][r] = ok ? sv : -1e30f;
            }
        }

        // ---- online softmax (row spread over 16 lanes x 4 cgs) ----------
        float mx[4];
#pragma unroll
        for (int r = 0; r < 4; ++r) {
            mx[r] = fmaxf(fmaxf(s[0][r], s[1][r]), fmaxf(s[2][r], s[3][r]));
#pragma unroll
            for (int d = 1; d < 16; d <<= 1) mx[r] = fmaxf(mx[r], __shfl_xor(mx[r], d));
        }
        float resc[4];
#pragma unroll
        for (int r = 0; r < 4; ++r) {
            float mn = fmaxf(m[r], mx[r]);
            resc[r] = __expf(m[r] - mn);
            m[r] = mn;
        }
        float rs[4] = {0.f, 0.f, 0.f, 0.f};
#pragma unroll
        for (int cg = 0; cg < 4; ++cg)
#pragma unroll
            for (int r = 0; r < 4; ++r) {
                float sv = s[cg][r];
                float p = (sv > -5e29f) ? __expf(sv - m[r]) : 0.f;  // masked -> exactly 0
                s[cg][r] = p;
                rs[r] += p;
            }
#pragma unroll
        for (int r = 0; r < 4; ++r) {
#pragma unroll
            for (int d = 1; d < 16; d <<= 1) rs[r] += __shfl_xor(rs[r], d);
            lsum[r] = lsum[r] * resc[r] + rs[r];
        }
#pragma unroll
        for (int cg = 0; cg < 4; ++cg)
#pragma unroll
            for (int r = 0; r < 4; ++r) acc_o[cg][r] *= resc[r];

        // ---- P -> LDS (bf16, XOR swizzle: byte ^= (row&7)<<4) -----------
        char* pb = &plds[w][kt & 1][0];
#pragma unroll
        for (int cg = 0; cg < 4; ++cg)
#pragma unroll
            for (int r = 0; r < 4; ++r) {
                int row = lhi * 4 + r;
                int col = cg * 16 + l15;
                int byte = (row * 128 + col * 2) ^ ((row & 7) << 4);
                *(bf16_t*)(pb + byte) = (bf16_t)s[cg][r];
            }

        // ---- O += P . V  (A-frags from LDS, B-frags from vhT, contiguous)
        const bf16_t* vbase = vhT + ((size_t)(b * NH + l15) << 11) + kt * 64 + lhi * 8;
#pragma unroll
        for (int kc = 0; kc < 2; ++kc) {
            int row = l15;
            int byte = (row * 128 + kc * 64 + lhi * 16) ^ ((row & 7) << 4);
            bf16x8 pf = *(bf16x8*)(pb + byte);
#pragma unroll
            for (int cg = 0; cg < 4; ++cg) {
                bf16x8 vf = *(const bf16x8*)(vbase + ((size_t)cg * 16 << 11) + kc * 32);
                acc_o[cg] = MFMA16(pf, vf, acc_o[cg]);
            }
        }
    }

    // ---- write this wave's partials to LDS ------------------------------
#pragma unroll
    for (int cg = 0; cg < 4; ++cg)
#pragma unroll
        for (int r = 0; r < 4; ++r)
            sm_o[w][lhi * 4 + r][cg * 16 + l15] = acc_o[cg][r];
    if (l15 == 0) {
#pragma unroll
        for (int r = 0; r < 4; ++r) {
            sm_ml[w][0][lhi * 4 + r] = m[r];
            sm_ml[w][1][lhi * 4 + r] = lsum[r];
        }
    }
    __syncthreads();

    // ---- merge 4 splits; this thread covers col = w*16+l15, rows lhi*4+r
#pragma unroll
    for (int r = 0; r < 4; ++r) {
        int row = lhi * 4 + r;
        float mg = -1e30f;
#pragma unroll
        for (int s = 0; s < 4; ++s) mg = fmaxf(mg, sm_ml[s][0][row]);
        float lg = 0.f, og = 0.f;
#pragma unroll
        for (int s = 0; s < 4; ++s) {
            float e = __expf(sm_ml[s][0][row] - mg);
            lg += e * sm_ml[s][1][row];
            og += e * sm_o[s][row][w * 16 + l15];
        }
        out[(size_t)(b * NT + q0 + row) * NH + w * 16 + l15] = og / lg;
    }
}

// ---------------------------------------------------------------------------
extern "C" void kernel_launch(void* const* d_in, const int* in_sizes, int n_in,
                              void* d_out, int out_size, void* d_ws, size_t ws_size,
                              hipStream_t stream)
{
    const float* k_in = (const float*)d_in[0];
    const float* q_in = (const float*)d_in[1];
    const float* v_in = (const float*)d_in[2];
    const int*   mask = (const int*)d_in[3];
    const float* Wk   = (const float*)d_in[4];
    const float* Wq   = (const float*)d_in[5];
    const float* Wv   = (const float*)d_in[6];
    float* out = (float*)d_out;

    char* ws = (char*)d_ws;
    bf16_t* Wb  = (bf16_t*)ws;                       // 3*64*1024 bf16 = 384 KB
    bf16_t* qh  = (bf16_t*)(ws + 3 * NH * NE * 2);   // 16384*64 bf16 = 2 MB
    bf16_t* kh  = qh + (size_t)NB * NT * NH;
    bf16_t* vhT = kh + (size_t)NB * NT * NH;         // [8][64][2048] bf16 = 2 MB

    convw_kernel<<<dim3(32, 3), 256, 0, stream>>>(Wq, Wk, Wv, Wb);
    proj_kernel<<<dim3(NB * NT / 64, 3), 256, 0, stream>>>(q_in, k_in, v_in, Wb, qh, kh, vhT);
    attn_kernel<<<dim3(NB * NT / 16), 256, 0, stream>>>(qh, kh, vhT, mask, out);
}